// Round 16
// baseline (459.045 us; speedup 1.0000x reference)
//
#include <hip/hip_runtime.h>

#define DIM 512
#define H 256
#define W 256
#define TS 8           // output tile side (cells)
#define HS 14          // halo side = TS + 6
#define NH (HS * HS)   // 196 halo cells
#define CG 64          // channels per block
#define NTX (W / TS)   // 32 tiles per row

// ---------------------------------------------------------------------------
// Fused prep kernel (unchanged — measured good).
// Blocks 0..48: fold 3 depthwise kernels into one 7x7 tap table (transposed
// grid => tap w[c, dw+pad, dh+pad]) + bias sum. Blocks 49..: scatter point
// indices onto cell->index map. NO memset: consumers validate entries.
// ---------------------------------------------------------------------------
__global__ __launch_bounds__(512) void prep_kernel(
    const int* __restrict__ pos, int n,
    const float* __restrict__ k3, const float* __restrict__ b1,
    const float* __restrict__ k5, const float* __restrict__ b2,
    const float* __restrict__ k7, const float* __restrict__ b3,
    float* __restrict__ weff, float* __restrict__ bsum,
    int* __restrict__ map) {
    int b = blockIdx.x;
    if (b < 49) {
        int o = b;             // 0..48
        int c = threadIdx.x;   // 0..511
        int dh = o / 7 - 3, dw = o % 7 - 3;
        float v = k7[c * 49 + (dw + 3) * 7 + (dh + 3)];
        if (dh >= -2 && dh <= 2 && dw >= -2 && dw <= 2)
            v += k5[c * 25 + (dw + 2) * 5 + (dh + 2)];
        if (dh >= -1 && dh <= 1 && dw >= -1 && dw <= 1)
            v += k3[c * 9 + (dw + 1) * 3 + (dh + 1)];
        weff[o * DIM + c] = v;
        if (o == 0) bsum[c] = b1[c] + b2[c] + b3[c];
    } else {
        int i = (b - 49) * 512 + threadIdx.x;
        if (i < n) {
            int h = pos[2 * i], w = pos[2 * i + 1];
            map[h * W + w] = i;
        }
    }
}

// ---------------------------------------------------------------------------
// v4: LDS-tiled DENSE conv. Block = (8x8 tile) x (64-channel slice).
// Stage 14x14 halo x-slice into LDS (zeros where unoccupied -> inner loop is
// maskless). weff slice (49 floats) + bias in registers. 4 waves x 2 output
// rows; halo rows loaded once serve both rows (u=t / u=t-1). All LDS access
// conflict-free (lane-major). Only occupied cells are written back.
// out[j,c] = sum_{u,v} Weff[u*7+v,c] * xs[cy+u][cx+v] + x[j,c] + bsum[c]
// ---------------------------------------------------------------------------
__global__ __launch_bounds__(256, 3) void tile_conv_kernel(
    const float* __restrict__ x, const int2* __restrict__ pos2,
    const int* __restrict__ map, const float* __restrict__ weff,
    const float* __restrict__ bsum, float* __restrict__ out, int n) {

    __shared__ float xs[NH][CG];
    __shared__ int s_j[TS * TS];

    int bid = blockIdx.x;
    int cg = bid & 7;          // channel group (fastest -> per-XCD slice residency)
    int tile = bid >> 3;
    int ty = tile >> 5, tx = tile & (NTX - 1);
    int th0 = ty * TS, tw0 = tx * TS;

    int tid = threadIdx.x;
    int wv = tid >> 6, lane = tid & 63;
    int cbase = cg * CG + lane;          // this lane's channel

    // weight slice + bias into registers (overlaps staging latency)
    float wr[49];
    #pragma unroll
    for (int o = 0; o < 49; ++o) wr[o] = weff[o * DIM + cbase];
    float bs = bsum[cbase];

    // ---- stage halo (zero-fill unoccupied / OOB); record inner-cell ids ----
    for (int hc = wv; hc < NH; hc += 4) {
        int hy = hc / HS, hx = hc % HS;
        int gh = th0 - 3 + hy, gw = tw0 - 3 + hx;
        int j = -1;
        if (gh >= 0 && gh < H && gw >= 0 && gw < W) {
            int jj = map[gh * W + gw];
            if ((unsigned)jj < (unsigned)n) {
                int2 pj = pos2[jj];
                if (pj.x == gh && pj.y == gw) j = jj;
            }
        }
        float xv = (j >= 0) ? x[(size_t)j * DIM + cbase] : 0.0f;
        xs[hc][lane] = xv;
        if (lane == 0 && hy >= 3 && hy < 3 + TS && hx >= 3 && hx < 3 + TS)
            s_j[(hy - 3) * TS + (hx - 3)] = j;
    }
    __syncthreads();

    // ---- dense conv: wave wv owns output rows r0, r0+1 ----
    int r0 = wv * 2;
    float acc0[TS], acc1[TS];
    #pragma unroll
    for (int cx = 0; cx < TS; ++cx) { acc0[cx] = 0.0f; acc1[cx] = 0.0f; }

    #pragma unroll
    for (int t = 0; t < 8; ++t) {      // halo rows r0+t serve row0(u=t), row1(u=t-1)
        float xr[HS];
        #pragma unroll
        for (int m = 0; m < HS; ++m) xr[m] = xs[(r0 + t) * HS + m][lane];
        if (t < 7) {
            #pragma unroll
            for (int v = 0; v < 7; ++v)
                #pragma unroll
                for (int cx = 0; cx < TS; ++cx)
                    acc0[cx] = fmaf(wr[t * 7 + v], xr[cx + v], acc0[cx]);
        }
        if (t >= 1) {
            #pragma unroll
            for (int v = 0; v < 7; ++v)
                #pragma unroll
                for (int cx = 0; cx < TS; ++cx)
                    acc1[cx] = fmaf(wr[(t - 1) * 7 + v], xr[cx + v], acc1[cx]);
        }
    }

    // ---- epilogue: occupied cells only; identity from LDS (center cell) ----
    #pragma unroll
    for (int cx = 0; cx < TS; ++cx) {
        int j0 = s_j[r0 * TS + cx];
        if (j0 >= 0)
            out[(size_t)j0 * DIM + cbase] =
                acc0[cx] + xs[(r0 + 3) * HS + (cx + 3)][lane] + bs;
        int j1 = s_j[(r0 + 1) * TS + cx];
        if (j1 >= 0)
            out[(size_t)j1 * DIM + cbase] =
                acc1[cx] + xs[(r0 + 4) * HS + (cx + 3)][lane] + bs;
    }
}

extern "C" void kernel_launch(void* const* d_in, const int* in_sizes, int n_in,
                              void* d_out, int out_size, void* d_ws, size_t ws_size,
                              hipStream_t stream) {
    const float* x   = (const float*)d_in[0];
    const int*   pos = (const int*)d_in[1];
    const float* k3  = (const float*)d_in[2];
    const float* b1  = (const float*)d_in[3];
    const float* k5  = (const float*)d_in[4];
    const float* b2  = (const float*)d_in[5];
    const float* k7  = (const float*)d_in[6];
    const float* b3  = (const float*)d_in[7];
    float* out = (float*)d_out;

    char* ws = (char*)d_ws;
    int*   map  = (int*)ws;                                   // H*W*4   = 256 KB
    float* weff = (float*)(ws + (size_t)H * W * 4);           // 49*512*4 ~ 100 KB
    float* bsum = (float*)(ws + (size_t)H * W * 4 + 49 * DIM * 4);  // 2 KB

    int n = in_sizes[1] / 2;  // N points

    int scatter_blocks = (n + 511) / 512;
    prep_kernel<<<49 + scatter_blocks, 512, 0, stream>>>(
        pos, n, k3, b1, k5, b2, k7, b3, weff, bsum, map);

    int ntiles = (H / TS) * (W / TS);        // 1024
    int nblocks = ntiles * (DIM / CG);       // 8192
    tile_conv_kernel<<<nblocks, 256, 0, stream>>>(
        x, (const int2*)pos, map, weff, bsum, out, n);
}